// Round 6
// baseline (499.800 us; speedup 1.0000x reference)
//
#include <hip/hip_runtime.h>
#include <math.h>

namespace {
constexpr int B_ = 4;
constexpr int N_ = 2048;
constexpr int K_ = 48;
constexpr int MAX_REL_ = 32;
constexpr int EDGE_C_ = 128;
constexpr int NUM_PE_ = 16;
constexpr int NROWS = B_ * N_;      // 8192
constexpr int NEDGE = NROWS * K_;   // 393216
}

// ---------------- kernel 1: X4 = {coords[center]*m, m} ----------------
__global__ __launch_bounds__(256) void x_kernel(const float* __restrict__ coords,
                                                const float* __restrict__ mask,
                                                const int* __restrict__ t2ca,
                                                float4* __restrict__ X4) {
    int r = blockIdx.x * 256 + threadIdx.x;
    if (r >= NROWS) return;
    int b = r >> 11;                 // N_ = 2048
    int c = t2ca[r];
    float m = mask[r];
    const float* s = coords + ((size_t)(b * N_ + c)) * 3;
    X4[r] = make_float4(__fmul_rn(s[0], m), __fmul_rn(s[1], m),
                        __fmul_rn(s[2], m), m);
}

// ---------------- prep: ONE single-block kernel, staged via syncthreads ------
// stage 1: center edge_w rows (sW), export Wg = centered[16:33] * ln_g
// stage 2: sC[d,:] = (pe_w[d,:]+pe_b) @ sW[0:16,:]; export C1g = sC * ln_g
// stage 3: variance tables (1443 dot-128s, one per thread-slot):
//   var(edge) = V0[d] + T12_2[d]·rbf + rbf^T A22 rbf
//             + tb*(Tb1_2[d] + A23_2·rbf) + tb^2*A33
// LDS rows padded to 129 floats so stage-3 column dots don't alias banks.
__global__ __launch_bounds__(256) void prep_kernel(const float* __restrict__ pe_w,
                                                   const float* __restrict__ pe_b,
                                                   const float* __restrict__ edge_w,
                                                   const float* __restrict__ ln_g,
                                                   float* __restrict__ Wg,
                                                   float* __restrict__ C1g,
                                                   float* __restrict__ T12_2,
                                                   float* __restrict__ A22,
                                                   float* __restrict__ A23_2,
                                                   float* __restrict__ V0,
                                                   float* __restrict__ Tb1_2,
                                                   float* __restrict__ A33) {
    __shared__ float sW[33][129];    // 16.6 KB
    __shared__ float sC[65][129];    // 32.8 KB
    __shared__ float sm[33];
    const int tid = threadIdx.x;
    const int wv = tid >> 6;
    const int lane = tid & 63;

    for (int idx = tid; idx < 33 * 128; idx += 256)
        sW[idx >> 7][idx & 127] = edge_w[idx];
    __syncthreads();
    for (int r = wv; r < 33; r += 4) {
        float v = sW[r][lane] + sW[r][64 + lane];
        #pragma unroll
        for (int off = 32; off; off >>= 1) v += __shfl_xor(v, off, 64);
        if (lane == 0) sm[r] = v * (1.0f / 128.0f);
    }
    __syncthreads();
    for (int idx = tid; idx < 33 * 128; idx += 256) {
        int p = idx >> 7, c = idx & 127;
        float cen = sW[p][c] - sm[p];
        sW[p][c] = cen;
        if (p >= 16) Wg[(p - 16) * 128 + c] = cen * ln_g[c];
    }
    __syncthreads();
    for (int idx = tid; idx < 65 * 128; idx += 256) {
        int d = idx >> 7, c = idx & 127;
        float acc = 0.0f;
        #pragma unroll
        for (int q = 0; q < 16; ++q)
            acc = fmaf(pe_w[d * 16 + q] + pe_b[q], sW[q][c], acc);
        sC[d][c] = acc;
        C1g[idx] = acc * ln_g[c];
    }
    __syncthreads();
    for (int idx = tid; idx < 1443; idx += 256) {
        const float* u; const float* v; float scale; float* dst;
        if (idx < 1040) {
            int d = idx >> 4, r = idx & 15;
            u = &sC[d][0]; v = &sW[16 + r][0];
            scale = 2.0f / 128.0f; dst = T12_2 + idx;
        } else if (idx < 1105) {
            int d = idx - 1040;
            u = &sC[d][0]; v = u; scale = 1.0f / 128.0f; dst = V0 + d;
        } else if (idx < 1170) {
            int d = idx - 1105;
            u = &sC[d][0]; v = &sW[32][0]; scale = 2.0f / 128.0f; dst = Tb1_2 + d;
        } else if (idx < 1426) {
            int i = idx - 1170; int r = i >> 4, s = i & 15;
            u = &sW[16 + r][0]; v = &sW[16 + s][0];
            scale = 1.0f / 128.0f; dst = A22 + i;
        } else if (idx < 1442) {
            int r = idx - 1426;
            u = &sW[16 + r][0]; v = &sW[32][0];
            scale = 2.0f / 128.0f; dst = A23_2 + r;
        } else {
            u = &sW[32][0]; v = u; scale = 1.0f / 128.0f; dst = A33;
        }
        float a = 0.0f;
        #pragma unroll 8
        for (int c = 0; c < 128; ++c) a = fmaf(u[c], v[c], a);
        *dst = a * scale;
    }
}

// ---------------- fused kernel: KNN + features + matmul per wave -------------
// One wave per row, 4 rows/block, ZERO __syncthreads (all shared state is
// per-wave; wave-synchronous lgkmcnt waits only).  Waves in knn's VALU phase
// overlap waves in edge's store phase on the same CU.
// KNN: float4 loads of {x,y,z,m}; register-only adjust (binary mask:
// adj = m2 ? D : Dmax == D + (1-m2)*Dmax bitwise for m in {0,1});
// radix-select exact 48th key; compact; wave bitonic sort.
// EDGE: algebraic LN (centered+g-scaled weights, variance via tables).
__global__ __launch_bounds__(256, 3) void fused_kernel(const float4* __restrict__ X4,
                                                       const float* __restrict__ token_bonds,
                                                       const float* __restrict__ C1g,
                                                       const float* __restrict__ Wg,
                                                       const float* __restrict__ V0,
                                                       const float* __restrict__ T12_2,
                                                       const float* __restrict__ Tb1_2,
                                                       const float* __restrict__ A22,
                                                       const float* __restrict__ A23_2,
                                                       const float* __restrict__ A33,
                                                       const float* __restrict__ ln_b,
                                                       const int* __restrict__ res_idx,
                                                       const int* __restrict__ is_lig,
                                                       float* __restrict__ Eout,
                                                       float* __restrict__ eidx_f,
                                                       float* __restrict__ dneb) {
    __shared__ unsigned s_hist[4][256];              // 4 KB
    __shared__ unsigned long long s_cbuf[4][64];     // 2 KB
    __shared__ float s_rbf[4][K_][20];               // 15 KB
    __shared__ float4 s_meta[4][K_];                 // 3 KB
    __shared__ float s_D[4][K_];                     // 768 B
    const int tid = threadIdx.x;
    const int wv = tid >> 6;
    const int lane = tid & 63;
    const int row = blockIdx.x * 4 + wv;     // grid = NROWS/4
    const int b = row >> 11;

    // ================= KNN phase =================
    const float4 xi = X4[row];
    const float mi = xi.w;
    const float4* Xb = X4 + (size_t)b * N_;

    unsigned fb[32];
    unsigned mz = 0u;
    float lmax = -INFINITY;
    #pragma unroll
    for (int t = 0; t < 32; ++t) {
        const int j = t * 64 + lane;
        const float4 p = Xb[j];
        float dx = __fsub_rn(xi.x, p.x);
        float dy = __fsub_rn(xi.y, p.y);
        float dz = __fsub_rn(xi.z, p.z);
        float d2 = __fmaf_rn(dz, dz, __fmaf_rn(dx, dx, __fmul_rn(dy, dy)));
        float m2 = __fmul_rn(mi, p.w);
        float dd = __fmul_rn(m2, __fsqrt_rn(__fadd_rn(d2, 1e-6f)));
        fb[t] = __float_as_uint(dd);
        if (m2 == 0.0f) mz |= (1u << t);
        lmax = fmaxf(lmax, dd);
    }
    #pragma unroll
    for (int off = 32; off; off >>= 1) lmax = fmaxf(lmax, __shfl_xor(lmax, off, 64));

    // adjust (register-only) + bit-range for key normalization
    unsigned fmin_l = 0xFFFFFFFFu, fmax_l = 0u;
    #pragma unroll
    for (int t = 0; t < 32; ++t) {
        float adj = ((mz >> t) & 1u) ? lmax : __uint_as_float(fb[t]);
        unsigned u = __float_as_uint(adj);
        fb[t] = u;
        fmin_l = min(fmin_l, u);
        fmax_l = max(fmax_l, u);
    }
    #pragma unroll
    for (int off = 32; off; off >>= 1) {
        fmin_l = min(fmin_l, (unsigned)__shfl_xor((int)fmin_l, off, 64));
        fmax_l = max(fmax_l, (unsigned)__shfl_xor((int)fmax_l, off, 64));
    }
    const unsigned fminb = fmin_l;
    const unsigned range = fmax_l - fminb;
    const int vbits = (range == 0u) ? 0 : (32 - __clz((int)range));
    const int L = vbits + 11;
    int sh = (L > 8) ? (L - 8) : 0;

    unsigned cand = 0xFFFFFFFFu;
    int k_rem = K_;
    unsigned long long T = 0ull;

    while (true) {
        s_hist[wv][4 * lane + 0] = 0u;
        s_hist[wv][4 * lane + 1] = 0u;
        s_hist[wv][4 * lane + 2] = 0u;
        s_hist[wv][4 * lane + 3] = 0u;
        __asm__ volatile("s_waitcnt lgkmcnt(0)" ::: "memory");
        #pragma unroll
        for (int t = 0; t < 32; ++t) {
            if ((cand >> t) & 1u) {
                unsigned dig;
                if (sh >= 11) {
                    dig = ((fb[t] - fminb) >> (sh - 11)) & 255u;
                } else {
                    unsigned long long key =
                        ((unsigned long long)(fb[t] - fminb) << 11)
                        | (unsigned long long)(unsigned)(t * 64 + lane);
                    dig = (unsigned)(key >> sh) & 255u;
                }
                atomicAdd(&s_hist[wv][dig], 1u);
            }
        }
        __asm__ volatile("s_waitcnt lgkmcnt(0)" ::: "memory");
        const unsigned c0 = s_hist[wv][4 * lane + 0];
        const unsigned c1 = s_hist[wv][4 * lane + 1];
        const unsigned c2 = s_hist[wv][4 * lane + 2];
        const unsigned c3 = s_hist[wv][4 * lane + 3];
        const unsigned s4 = c0 + c1 + c2 + c3;
        unsigned inc = s4;
        #pragma unroll
        for (int off = 1; off < 64; off <<= 1) {
            unsigned o = (unsigned)__shfl_up((int)inc, off, 64);
            if (lane >= off) inc += o;
        }
        const unsigned ex = inc - s4;
        const unsigned e1 = ex + c0, e2 = e1 + c1, e3 = e2 + c2;
        const unsigned kr = (unsigned)k_rem;
        int digl = -1; unsigned below = 0u, bc = 0u;
        if (ex < kr && kr <= e1)           { digl = 4 * lane + 0; below = ex; bc = c0; }
        else if (e1 < kr && kr <= e2)      { digl = 4 * lane + 1; below = e1; bc = c1; }
        else if (e2 < kr && kr <= e3)      { digl = 4 * lane + 2; below = e2; bc = c2; }
        else if (e3 < kr && kr <= e3 + c3) { digl = 4 * lane + 3; below = e3; bc = c3; }

        unsigned long long bal = __ballot(digl >= 0);
        int src = __ffsll((long long)bal) - 1;
        const int dstar = __shfl(digl, src, 64);
        below = (unsigned)__shfl((int)below, src, 64);
        bc    = (unsigned)__shfl((int)bc, src, 64);
        k_rem -= (int)below;

        unsigned nc = 0u;
        unsigned long long myT = 0ull;
        #pragma unroll
        for (int t = 0; t < 32; ++t) {
            if ((cand >> t) & 1u) {
                unsigned long long key =
                    ((unsigned long long)(fb[t] - fminb) << 11)
                    | (unsigned long long)(unsigned)(t * 64 + lane);
                unsigned dig;
                if (sh >= 11) dig = ((fb[t] - fminb) >> (sh - 11)) & 255u;
                else          dig = (unsigned)(key >> sh) & 255u;
                if (dig == (unsigned)dstar) { nc |= (1u << t); myT = key; }
            }
        }
        cand = nc;
        if (bc == 1u || sh == 0) {
            unsigned long long b2 = __ballot(cand != 0u);
            int owner = __ffsll((long long)b2) - 1;
            T = __shfl(myT, owner, 64);
            break;
        }
        sh = (sh > 8) ? (sh - 8) : 0;
    }

    // select keys <= T (exactly 48), compact to LDS
    const unsigned Tv = (unsigned)(T >> 11);
    const unsigned Tj = (unsigned)(T & 2047u);
    unsigned selm = 0u; int scnt = 0;
    #pragma unroll
    for (int t = 0; t < 32; ++t) {
        unsigned v = fb[t] - fminb;
        unsigned j = (unsigned)(t * 64 + lane);
        if (v < Tv || (v == Tv && j <= Tj)) { selm |= (1u << t); ++scnt; }
    }
    int isc = scnt;
    #pragma unroll
    for (int off = 1; off < 64; off <<= 1) {
        int o = __shfl_up(isc, off, 64);
        if (lane >= off) isc += o;
    }
    int pos = isc - scnt;
    #pragma unroll
    for (int t = 0; t < 32; ++t) {
        if ((selm >> t) & 1u) {
            s_cbuf[wv][pos] = ((unsigned long long)(fb[t] - fminb) << 11)
                            | (unsigned long long)(unsigned)(t * 64 + lane);
            ++pos;
        }
    }
    __asm__ volatile("s_waitcnt lgkmcnt(0)" ::: "memory");
    unsigned long long kk = (lane < K_) ? s_cbuf[wv][lane] : ~0ull;

    // wave bitonic sort of 64 (ascending)
    #pragma unroll
    for (int k2 = 2; k2 <= 64; k2 <<= 1) {
        #pragma unroll
        for (int j = k2 >> 1; j > 0; j >>= 1) {
            unsigned long long o = __shfl_xor(kk, j, 64);
            const bool dirAsc = ((lane & k2) == 0);
            const bool lower = ((lane & j) == 0);
            unsigned long long mn = (kk < o) ? kk : o;
            unsigned long long mx = (kk < o) ? o : kk;
            kk = (lower == dirAsc) ? mn : mx;
        }
    }

    // ================= EDGE phase =================
    // phase A: outputs + per-edge metadata (lane k owns edge k)
    const int ri = res_idx[row];
    const int li = is_lig[row];
    int doff_l = 0; float tb_l = 0.0f;
    if (lane < K_) {
        const unsigned fbits = (unsigned)(kk >> 11) + fminb;
        const unsigned ji = (unsigned)(kk & 2047u);
        const float D = __uint_as_float(fbits);
        dneb[(size_t)row * K_ + lane] = D;
        eidx_f[(size_t)row * K_ + lane] = (float)ji;
        s_D[wv][lane] = D;
        const int jrow = b * N_ + (int)ji;
        const int rj = res_idx[jrow];
        const int lj = is_lig[jrow];
        float tb = token_bonds[(size_t)row * N_ + ji];
        tb_l = (li | lj) ? tb : 0.0f;
        doff_l = min(max(ri - rj + MAX_REL_, 0), 2 * MAX_REL_);
    }
    __asm__ volatile("s_waitcnt lgkmcnt(0)" ::: "memory");

    // phase B: all 48x16 RBF values cooperatively
    #pragma unroll
    for (int t = 0; t < (K_ * NUM_PE_) / 64; ++t) {
        const int idx = t * 64 + lane;
        const int k = idx >> 4, r = idx & 15;
        const float D = s_D[wv][k];
        const float mu = 2.0f + (float)r * (4.0f / 3.0f);
        const float x = (D - mu) * 0.8f;
        s_rbf[wv][k][r] = __expf(-x * x);
    }
    __asm__ volatile("s_waitcnt lgkmcnt(0)" ::: "memory");

    // phase VAR: lane k computes rstd for edge k (tables L1-hot from global)
    if (lane < K_) {
        float rr[16];
        const float* rb = &s_rbf[wv][lane][0];
        *(float4*)&rr[0]  = *(const float4*)&rb[0];
        *(float4*)&rr[4]  = *(const float4*)&rb[4];
        *(float4*)&rr[8]  = *(const float4*)&rb[8];
        *(float4*)&rr[12] = *(const float4*)&rb[12];
        float var = V0[doff_l];
        const float4* t12 = (const float4*)(T12_2 + doff_l * 16);
        float4 q0 = t12[0], q1 = t12[1], q2 = t12[2], q3 = t12[3];
        var = fmaf(rr[0], q0.x, var);  var = fmaf(rr[1], q0.y, var);
        var = fmaf(rr[2], q0.z, var);  var = fmaf(rr[3], q0.w, var);
        var = fmaf(rr[4], q1.x, var);  var = fmaf(rr[5], q1.y, var);
        var = fmaf(rr[6], q1.z, var);  var = fmaf(rr[7], q1.w, var);
        var = fmaf(rr[8], q2.x, var);  var = fmaf(rr[9], q2.y, var);
        var = fmaf(rr[10], q2.z, var); var = fmaf(rr[11], q2.w, var);
        var = fmaf(rr[12], q3.x, var); var = fmaf(rr[13], q3.y, var);
        var = fmaf(rr[14], q3.z, var); var = fmaf(rr[15], q3.w, var);
        #pragma unroll
        for (int r = 0; r < 16; ++r) {
            const float4* arow = (const float4*)(A22 + r * 16);
            float tr = 0.0f;
            #pragma unroll
            for (int s4 = 0; s4 < 4; ++s4) {
                float4 a = arow[s4];
                tr = fmaf(rr[s4 * 4 + 0], a.x, tr);
                tr = fmaf(rr[s4 * 4 + 1], a.y, tr);
                tr = fmaf(rr[s4 * 4 + 2], a.z, tr);
                tr = fmaf(rr[s4 * 4 + 3], a.w, tr);
            }
            var = fmaf(rr[r], tr, var);
        }
        if (tb_l != 0.0f) {
            float extra = Tb1_2[doff_l];
            #pragma unroll
            for (int r = 0; r < 16; ++r) extra = fmaf(rr[r], A23_2[r], extra);
            var = fmaf(tb_l, extra, var);
            var = fmaf(tb_l * tb_l, A33[0], var);
        }
        const float rstd = rsqrtf(var + 1e-5f);
        s_meta[wv][lane] = make_float4((float)doff_l, tb_l, rstd, 0.0f);
    }
    __asm__ volatile("s_waitcnt lgkmcnt(0)" ::: "memory");

    // phase C: 24 iterations, 2 edges each (half-wave split, float4 channels)
    const int hl = lane & 31;
    const int eo = lane >> 5;
    float4 wgt[17];
    #pragma unroll
    for (int p = 0; p < 17; ++p)
        wgt[p] = ((const float4*)Wg)[p * 32 + hl];
    const float4 bb = ((const float4*)ln_b)[hl];

    float4* outp = (float4*)Eout + (size_t)row * K_ * 32 + hl;
    #pragma unroll 2
    for (int k = 0; k < K_; k += 2) {
        const float4 mt = s_meta[wv][k + eo];
        const int doffk = (int)mt.x;
        const float tbk = mt.y;
        const float rstd = mt.z;
        const float4 c1 = ((const float4*)(C1g + ((size_t)doffk << 7)))[hl];

        float rr[16];
        const float* rb = &s_rbf[wv][k + eo][0];
        *(float4*)&rr[0]  = *(const float4*)&rb[0];
        *(float4*)&rr[4]  = *(const float4*)&rb[4];
        *(float4*)&rr[8]  = *(const float4*)&rb[8];
        *(float4*)&rr[12] = *(const float4*)&rb[12];

        float ax = c1.x, ay = c1.y, az = c1.z, aw = c1.w;
        #pragma unroll
        for (int p = 0; p < 16; ++p) {
            ax = fmaf(rr[p], wgt[p].x, ax);
            ay = fmaf(rr[p], wgt[p].y, ay);
            az = fmaf(rr[p], wgt[p].z, az);
            aw = fmaf(rr[p], wgt[p].w, aw);
        }
        if (__any(tbk != 0.0f)) {
            ax = fmaf(tbk, wgt[16].x, ax);
            ay = fmaf(tbk, wgt[16].y, ay);
            az = fmaf(tbk, wgt[16].z, az);
            aw = fmaf(tbk, wgt[16].w, aw);
        }
        float4 o;
        o.x = fmaf(ax, rstd, bb.x);
        o.y = fmaf(ay, rstd, bb.y);
        o.z = fmaf(az, rstd, bb.z);
        o.w = fmaf(aw, rstd, bb.w);
        outp[(size_t)(k + eo) * 32] = o;
    }
}

extern "C" void kernel_launch(void* const* d_in, const int* in_sizes, int n_in,
                              void* d_out, int out_size, void* d_ws, size_t ws_size,
                              hipStream_t stream) {
    const float* coords      = (const float*)d_in[0];
    const float* mask        = (const float*)d_in[1];
    const float* token_bonds = (const float*)d_in[2];
    const float* pe_w        = (const float*)d_in[3];
    const float* pe_b        = (const float*)d_in[4];
    const float* edge_w      = (const float*)d_in[5];
    const float* ln_g        = (const float*)d_in[6];
    const float* ln_b        = (const float*)d_in[7];
    const int*   t2ca        = (const int*)d_in[8];
    const int*   res_idx     = (const int*)d_in[9];
    // d_in[10] (asym_id) unused: chain_labels = zeros in the reference
    const int*   is_lig      = (const int*)d_in[11];

    float* out    = (float*)d_out;
    float* Eout   = out;                               // NEDGE * 128
    float* eidx_f = out + (size_t)NEDGE * EDGE_C_;     // NEDGE (ints as floats)
    float* dneb   = eidx_f + NEDGE;                    // NEDGE

    // workspace layout (floats); float4-read tables kept 16B-aligned
    float4* X4  = (float4*)d_ws;                       // NROWS float4  (end 32768)
    float* Wg   = (float*)d_ws + (size_t)NROWS * 4;    // 17*128  (end 34944)
    float* C1g  = Wg + 17 * 128;                       // 65*128  (end 43264)
    float* T12  = C1g + 65 * 128;                      // 1040    (end 44304)
    float* A22  = T12 + 1040;                          // 256     (end 44560)
    float* A23  = A22 + 256;                           // 16      (end 44576)
    float* V0   = A23 + 16;                            // 65      (end 44641)
    float* Tb1  = V0 + 65;                             // 65      (end 44706)
    float* A33  = Tb1 + 65;                            // 1

    hipLaunchKernelGGL(x_kernel, dim3(NROWS / 256), dim3(256), 0, stream,
                       coords, mask, t2ca, X4);
    hipLaunchKernelGGL(prep_kernel, dim3(1), dim3(256), 0, stream,
                       pe_w, pe_b, edge_w, ln_g, Wg, C1g, T12, A22, A23, V0, Tb1, A33);
    hipLaunchKernelGGL(fused_kernel, dim3(NROWS / 4), dim3(256), 0, stream,
                       X4, token_bonds, C1g, Wg, V0, T12, Tb1, A22, A23, A33,
                       ln_b, res_idx, is_lig, Eout, eidx_f, dneb);
}

// Round 7
// 428.078 us; speedup vs baseline: 1.1675x; 1.1675x over previous
//
#include <hip/hip_runtime.h>
#include <math.h>

namespace {
constexpr int B_ = 4;
constexpr int N_ = 2048;
constexpr int K_ = 48;
constexpr int MAX_REL_ = 32;
constexpr int EDGE_C_ = 128;
constexpr int NUM_PE_ = 16;
constexpr int NROWS = B_ * N_;      // 8192
constexpr int NEDGE = NROWS * K_;   // 393216
}

// ---------------- kernel 1: X4 = {coords[center]*m, m} ----------------
__global__ __launch_bounds__(256) void x_kernel(const float* __restrict__ coords,
                                                const float* __restrict__ mask,
                                                const int* __restrict__ t2ca,
                                                float4* __restrict__ X4) {
    int r = blockIdx.x * 256 + threadIdx.x;
    if (r >= NROWS) return;
    int b = r >> 11;                 // N_ = 2048
    int c = t2ca[r];
    float m = mask[r];
    const float* s = coords + ((size_t)(b * N_ + c)) * 3;
    X4[r] = make_float4(__fmul_rn(s[0], m), __fmul_rn(s[1], m),
                        __fmul_rn(s[2], m), m);
}

// ---------------- prep: ONE single-block kernel, staged via syncthreads ------
// stage 1: center edge_w rows (sW), export Wg = centered[16:33] * ln_g
// stage 2: sC[d,:] = (pe_w[d,:]+pe_b) @ sW[0:16,:]; export C1g = sC * ln_g
// stage 3: variance tables (1443 dot-128s):
//   var(edge) = V0[d] + T12_2[d]·rbf + rbf^T A22 rbf
//             + tb*(Tb1_2[d] + A23_2·rbf) + tb^2*A33
__global__ __launch_bounds__(256) void prep_kernel(const float* __restrict__ pe_w,
                                                   const float* __restrict__ pe_b,
                                                   const float* __restrict__ edge_w,
                                                   const float* __restrict__ ln_g,
                                                   float* __restrict__ Wg,
                                                   float* __restrict__ C1g,
                                                   float* __restrict__ T12_2,
                                                   float* __restrict__ A22,
                                                   float* __restrict__ A23_2,
                                                   float* __restrict__ V0,
                                                   float* __restrict__ Tb1_2,
                                                   float* __restrict__ A33) {
    __shared__ float sW[33][129];    // 16.6 KB
    __shared__ float sC[65][129];    // 32.8 KB
    __shared__ float sm[33];
    const int tid = threadIdx.x;
    const int wv = tid >> 6;
    const int lane = tid & 63;

    for (int idx = tid; idx < 33 * 128; idx += 256)
        sW[idx >> 7][idx & 127] = edge_w[idx];
    __syncthreads();
    for (int r = wv; r < 33; r += 4) {
        float v = sW[r][lane] + sW[r][64 + lane];
        #pragma unroll
        for (int off = 32; off; off >>= 1) v += __shfl_xor(v, off, 64);
        if (lane == 0) sm[r] = v * (1.0f / 128.0f);
    }
    __syncthreads();
    for (int idx = tid; idx < 33 * 128; idx += 256) {
        int p = idx >> 7, c = idx & 127;
        float cen = sW[p][c] - sm[p];
        sW[p][c] = cen;
        if (p >= 16) Wg[(p - 16) * 128 + c] = cen * ln_g[c];
    }
    __syncthreads();
    for (int idx = tid; idx < 65 * 128; idx += 256) {
        int d = idx >> 7, c = idx & 127;
        float acc = 0.0f;
        #pragma unroll
        for (int q = 0; q < 16; ++q)
            acc = fmaf(pe_w[d * 16 + q] + pe_b[q], sW[q][c], acc);
        sC[d][c] = acc;
        C1g[idx] = acc * ln_g[c];
    }
    __syncthreads();
    for (int idx = tid; idx < 1443; idx += 256) {
        const float* u; const float* v; float scale; float* dst;
        if (idx < 1040) {
            int d = idx >> 4, r = idx & 15;
            u = &sC[d][0]; v = &sW[16 + r][0];
            scale = 2.0f / 128.0f; dst = T12_2 + idx;
        } else if (idx < 1105) {
            int d = idx - 1040;
            u = &sC[d][0]; v = u; scale = 1.0f / 128.0f; dst = V0 + d;
        } else if (idx < 1170) {
            int d = idx - 1105;
            u = &sC[d][0]; v = &sW[32][0]; scale = 2.0f / 128.0f; dst = Tb1_2 + d;
        } else if (idx < 1426) {
            int i = idx - 1170; int r = i >> 4, s = i & 15;
            u = &sW[16 + r][0]; v = &sW[16 + s][0];
            scale = 1.0f / 128.0f; dst = A22 + i;
        } else if (idx < 1442) {
            int r = idx - 1426;
            u = &sW[16 + r][0]; v = &sW[32][0];
            scale = 2.0f / 128.0f; dst = A23_2 + r;
        } else {
            u = &sW[32][0]; v = u; scale = 1.0f / 128.0f; dst = A33;
        }
        float a = 0.0f;
        #pragma unroll 8
        for (int c = 0; c < 128; ++c) a = fmaf(u[c], v[c], a);
        *dst = a * scale;
    }
}

// ---------------- kernel 2: masked distances + stable top-K (smallest) --------
// One wave per row; 4 rows per 256-thread block.  X4 packed loads: ONE
// float4 VMEM per j (was 4 scalar loads), adjust pass register-only
// (binary mask: adj = m2==0 ? Dmax : D, bit-exact vs D+(1-m2)*Dmax).
// Radix-select exact 48th key; compact; wave bitonic sort of 64.
// Separate kernel => no write stream => X4 (128 KB) stays L2-resident.
__global__ __launch_bounds__(256) void knn_kernel(const float4* __restrict__ X4,
                                                  float* __restrict__ eidx_f,
                                                  float* __restrict__ dneb) {
    __shared__ unsigned s_hist[4][256];              // 4 KB
    __shared__ unsigned long long s_cbuf[4][64];     // 2 KB
    const int wv = threadIdx.x >> 6;
    const int lane = threadIdx.x & 63;
    const int row = blockIdx.x * 4 + wv;     // grid = NROWS/4
    const int b = row >> 11;

    const float4 xi = X4[row];
    const float mi = xi.w;
    const float4* Xb = X4 + (size_t)b * N_;

    // pass 1: one float4 load per j; D bits + zero-mask bits + row max
    unsigned fb[32];
    unsigned mz = 0u;
    float lmax = -INFINITY;
    #pragma unroll
    for (int t = 0; t < 32; ++t) {
        const int j = t * 64 + lane;
        const float4 p = Xb[j];
        float dx = __fsub_rn(xi.x, p.x);
        float dy = __fsub_rn(xi.y, p.y);
        float dz = __fsub_rn(xi.z, p.z);
        float d2 = __fmaf_rn(dz, dz, __fmaf_rn(dx, dx, __fmul_rn(dy, dy)));
        float m2 = __fmul_rn(mi, p.w);
        float dd = __fmul_rn(m2, __fsqrt_rn(__fadd_rn(d2, 1e-6f)));
        fb[t] = __float_as_uint(dd);
        if (m2 == 0.0f) mz |= (1u << t);
        lmax = fmaxf(lmax, dd);
    }
    #pragma unroll
    for (int off = 32; off; off >>= 1) lmax = fmaxf(lmax, __shfl_xor(lmax, off, 64));

    // pass 2 (register-only): adjust + bit-range for key normalization
    unsigned fmin_l = 0xFFFFFFFFu, fmax_l = 0u;
    #pragma unroll
    for (int t = 0; t < 32; ++t) {
        float adj = ((mz >> t) & 1u) ? lmax : __uint_as_float(fb[t]);
        unsigned u = __float_as_uint(adj);
        fb[t] = u;
        fmin_l = min(fmin_l, u);
        fmax_l = max(fmax_l, u);
    }
    #pragma unroll
    for (int off = 32; off; off >>= 1) {
        fmin_l = min(fmin_l, (unsigned)__shfl_xor((int)fmin_l, off, 64));
        fmax_l = max(fmax_l, (unsigned)__shfl_xor((int)fmax_l, off, 64));
    }
    const unsigned fminb = fmin_l;
    const unsigned range = fmax_l - fminb;
    const int vbits = (range == 0u) ? 0 : (32 - __clz((int)range));
    const int L = vbits + 11;
    int sh = (L > 8) ? (L - 8) : 0;

    unsigned cand = 0xFFFFFFFFu;
    int k_rem = K_;
    unsigned long long T = 0ull;

    while (true) {
        s_hist[wv][4 * lane + 0] = 0u;
        s_hist[wv][4 * lane + 1] = 0u;
        s_hist[wv][4 * lane + 2] = 0u;
        s_hist[wv][4 * lane + 3] = 0u;
        __asm__ volatile("s_waitcnt lgkmcnt(0)" ::: "memory");
        #pragma unroll
        for (int t = 0; t < 32; ++t) {
            if ((cand >> t) & 1u) {
                unsigned dig;
                if (sh >= 11) {
                    dig = ((fb[t] - fminb) >> (sh - 11)) & 255u;
                } else {
                    unsigned long long key =
                        ((unsigned long long)(fb[t] - fminb) << 11)
                        | (unsigned long long)(unsigned)(t * 64 + lane);
                    dig = (unsigned)(key >> sh) & 255u;
                }
                atomicAdd(&s_hist[wv][dig], 1u);
            }
        }
        __asm__ volatile("s_waitcnt lgkmcnt(0)" ::: "memory");
        const unsigned c0 = s_hist[wv][4 * lane + 0];
        const unsigned c1 = s_hist[wv][4 * lane + 1];
        const unsigned c2 = s_hist[wv][4 * lane + 2];
        const unsigned c3 = s_hist[wv][4 * lane + 3];
        const unsigned s4 = c0 + c1 + c2 + c3;
        unsigned inc = s4;
        #pragma unroll
        for (int off = 1; off < 64; off <<= 1) {
            unsigned o = (unsigned)__shfl_up((int)inc, off, 64);
            if (lane >= off) inc += o;
        }
        const unsigned ex = inc - s4;
        const unsigned e1 = ex + c0, e2 = e1 + c1, e3 = e2 + c2;
        const unsigned kr = (unsigned)k_rem;
        int digl = -1; unsigned below = 0u, bc = 0u;
        if (ex < kr && kr <= e1)           { digl = 4 * lane + 0; below = ex; bc = c0; }
        else if (e1 < kr && kr <= e2)      { digl = 4 * lane + 1; below = e1; bc = c1; }
        else if (e2 < kr && kr <= e3)      { digl = 4 * lane + 2; below = e2; bc = c2; }
        else if (e3 < kr && kr <= e3 + c3) { digl = 4 * lane + 3; below = e3; bc = c3; }

        unsigned long long bal = __ballot(digl >= 0);
        int src = __ffsll((long long)bal) - 1;
        const int dstar = __shfl(digl, src, 64);
        below = (unsigned)__shfl((int)below, src, 64);
        bc    = (unsigned)__shfl((int)bc, src, 64);
        k_rem -= (int)below;

        unsigned nc = 0u;
        unsigned long long myT = 0ull;
        #pragma unroll
        for (int t = 0; t < 32; ++t) {
            if ((cand >> t) & 1u) {
                unsigned long long key =
                    ((unsigned long long)(fb[t] - fminb) << 11)
                    | (unsigned long long)(unsigned)(t * 64 + lane);
                unsigned dig;
                if (sh >= 11) dig = ((fb[t] - fminb) >> (sh - 11)) & 255u;
                else          dig = (unsigned)(key >> sh) & 255u;
                if (dig == (unsigned)dstar) { nc |= (1u << t); myT = key; }
            }
        }
        cand = nc;
        if (bc == 1u || sh == 0) {
            unsigned long long b2 = __ballot(cand != 0u);
            int owner = __ffsll((long long)b2) - 1;
            T = __shfl(myT, owner, 64);
            break;
        }
        sh = (sh > 8) ? (sh - 8) : 0;
    }

    // select keys <= T (exactly 48), compact to LDS
    const unsigned Tv = (unsigned)(T >> 11);
    const unsigned Tj = (unsigned)(T & 2047u);
    unsigned selm = 0u; int scnt = 0;
    #pragma unroll
    for (int t = 0; t < 32; ++t) {
        unsigned v = fb[t] - fminb;
        unsigned j = (unsigned)(t * 64 + lane);
        if (v < Tv || (v == Tv && j <= Tj)) { selm |= (1u << t); ++scnt; }
    }
    int isc = scnt;
    #pragma unroll
    for (int off = 1; off < 64; off <<= 1) {
        int o = __shfl_up(isc, off, 64);
        if (lane >= off) isc += o;
    }
    int pos = isc - scnt;
    #pragma unroll
    for (int t = 0; t < 32; ++t) {
        if ((selm >> t) & 1u) {
            s_cbuf[wv][pos] = ((unsigned long long)(fb[t] - fminb) << 11)
                            | (unsigned long long)(unsigned)(t * 64 + lane);
            ++pos;
        }
    }
    __asm__ volatile("s_waitcnt lgkmcnt(0)" ::: "memory");
    unsigned long long kk = (lane < K_) ? s_cbuf[wv][lane] : ~0ull;

    // wave bitonic sort of 64 (ascending)
    #pragma unroll
    for (int k2 = 2; k2 <= 64; k2 <<= 1) {
        #pragma unroll
        for (int j = k2 >> 1; j > 0; j >>= 1) {
            unsigned long long o = __shfl_xor(kk, j, 64);
            const bool dirAsc = ((lane & k2) == 0);
            const bool lower = ((lane & j) == 0);
            unsigned long long mn = (kk < o) ? kk : o;
            unsigned long long mx = (kk < o) ? o : kk;
            kk = (lower == dirAsc) ? mn : mx;
        }
    }

    if (lane < K_) {
        unsigned fbits = (unsigned)(kk >> 11) + fminb;
        unsigned ji = (unsigned)(kk & 2047u);
        dneb[(size_t)row * K_ + lane] = __uint_as_float(fbits);
        eidx_f[(size_t)row * K_ + lane] = (float)ji;
    }
}

// ---------------- kernel 3: features -> centered+scaled matmul ---------------
// Full wave per edge, 2 channels/lane (float2), lean registers (34 weight
// VGPRs).  Meta {doff,tb,rstd} in one ds_read_b128 broadcast.  Algebraic LN
// (centered+g-scaled weights, variance via tables).  Eout stores are
// NONTEMPORAL (write-only stream, never re-read) to keep L2 for gathers.
__global__ __launch_bounds__(256, 4) void edge_kernel(const float* __restrict__ eidx_f,
                                                      const float* __restrict__ dneb,
                                                      const float* __restrict__ token_bonds,
                                                      const float* __restrict__ C1g,
                                                      const float* __restrict__ Wg,
                                                      const float* __restrict__ V0,
                                                      const float* __restrict__ T12_2,
                                                      const float* __restrict__ Tb1_2,
                                                      const float* __restrict__ A22,
                                                      const float* __restrict__ A23_2,
                                                      const float* __restrict__ A33,
                                                      const float* __restrict__ ln_b,
                                                      const int* __restrict__ res_idx,
                                                      const int* __restrict__ is_lig,
                                                      float* __restrict__ Eout) {
    __shared__ float s_rbf[4][K_][20];     // 15 KB
    __shared__ float4 s_meta[4][K_];       // {doff_f, tb, rstd, 0}
    __shared__ float s_D[4][K_];
    const int tid = threadIdx.x;
    const int wv = tid >> 6;
    const int lane = tid & 63;
    const int row = blockIdx.x * 4 + wv;      // grid = NROWS/4, one row per wave
    const int b = row >> 11;

    // centered+g-scaled rbf(16)+bond(1) weight columns: 34 VGPRs
    float w0[17], w1[17];
    #pragma unroll
    for (int p = 0; p < 17; ++p) {
        float2 w = ((const float2*)Wg)[p * 64 + lane];
        w0[p] = w.x; w1[p] = w.y;
    }
    const float bb0 = ln_b[2 * lane], bb1 = ln_b[2 * lane + 1];

    const int ri = res_idx[row];
    const int li = is_lig[row];

    // ---- phase A: batched per-edge metadata (lane k owns edge k) ----
    int doff_l = 0; float tb_l = 0.0f;
    if (lane < K_) {
        const int e = row * K_ + lane;
        const int j = (int)(eidx_f[e] + 0.5f);
        const float D = dneb[e];
        const int jrow = b * N_ + j;
        const int rj = res_idx[jrow];
        const int lj = is_lig[jrow];
        float tb = token_bonds[(size_t)row * N_ + j];
        tb_l = (li | lj) ? tb : 0.0f;
        doff_l = min(max(ri - rj + MAX_REL_, 0), 2 * MAX_REL_);
        s_D[wv][lane] = D;
    }
    __syncthreads();

    // ---- phase B: all 48x16 RBF values cooperatively ----
    #pragma unroll
    for (int t = 0; t < (K_ * NUM_PE_) / 64; ++t) {
        const int idx = t * 64 + lane;
        const int k = idx >> 4, r = idx & 15;
        const float D = s_D[wv][k];
        const float mu = 2.0f + (float)r * (4.0f / 3.0f);
        const float x = (D - mu) * 0.8f;
        s_rbf[wv][k][r] = __expf(-x * x);
    }
    __syncthreads();

    // ---- phase VAR: lane k computes rstd for edge k; writes packed meta ----
    if (lane < K_) {
        float rr[16];
        const float* rb = &s_rbf[wv][lane][0];
        *(float4*)&rr[0]  = *(const float4*)&rb[0];
        *(float4*)&rr[4]  = *(const float4*)&rb[4];
        *(float4*)&rr[8]  = *(const float4*)&rb[8];
        *(float4*)&rr[12] = *(const float4*)&rb[12];
        float var = V0[doff_l];
        const float4* t12 = (const float4*)(T12_2 + doff_l * 16);
        float4 q0 = t12[0], q1 = t12[1], q2 = t12[2], q3 = t12[3];
        var = fmaf(rr[0], q0.x, var);  var = fmaf(rr[1], q0.y, var);
        var = fmaf(rr[2], q0.z, var);  var = fmaf(rr[3], q0.w, var);
        var = fmaf(rr[4], q1.x, var);  var = fmaf(rr[5], q1.y, var);
        var = fmaf(rr[6], q1.z, var);  var = fmaf(rr[7], q1.w, var);
        var = fmaf(rr[8], q2.x, var);  var = fmaf(rr[9], q2.y, var);
        var = fmaf(rr[10], q2.z, var); var = fmaf(rr[11], q2.w, var);
        var = fmaf(rr[12], q3.x, var); var = fmaf(rr[13], q3.y, var);
        var = fmaf(rr[14], q3.z, var); var = fmaf(rr[15], q3.w, var);
        #pragma unroll
        for (int r = 0; r < 16; ++r) {
            const float4* arow = (const float4*)(A22 + r * 16);
            float tr = 0.0f;
            #pragma unroll
            for (int s4 = 0; s4 < 4; ++s4) {
                float4 a = arow[s4];
                tr = fmaf(rr[s4 * 4 + 0], a.x, tr);
                tr = fmaf(rr[s4 * 4 + 1], a.y, tr);
                tr = fmaf(rr[s4 * 4 + 2], a.z, tr);
                tr = fmaf(rr[s4 * 4 + 3], a.w, tr);
            }
            var = fmaf(rr[r], tr, var);
        }
        if (tb_l != 0.0f) {
            float extra = Tb1_2[doff_l];
            #pragma unroll
            for (int r = 0; r < 16; ++r) extra = fmaf(rr[r], A23_2[r], extra);
            var = fmaf(tb_l, extra, var);
            var = fmaf(tb_l * tb_l, A33[0], var);
        }
        const float rstd = rsqrtf(var + 1e-5f);
        s_meta[wv][lane] = make_float4((float)doff_l, tb_l, rstd, 0.0f);
    }
    __syncthreads();

    // ---- phase C: 48 edges, full wave each, float2 nontemporal stores ----
    unsigned long long* outp =
        (unsigned long long*)Eout + (size_t)row * K_ * 64 + lane;
    #pragma unroll 4
    for (int k = 0; k < K_; ++k) {
        const float4 mt = s_meta[wv][k];      // broadcast ds_read_b128
        const int doffk = (int)mt.x;
        const float tbk = mt.y;
        const float rstd = mt.z;
        const float2 c1 = *(const float2*)(C1g + ((size_t)doffk << 7) + 2 * lane);

        float rr[16];
        const float* rb = &s_rbf[wv][k][0];
        *(float4*)&rr[0]  = *(const float4*)&rb[0];
        *(float4*)&rr[4]  = *(const float4*)&rb[4];
        *(float4*)&rr[8]  = *(const float4*)&rb[8];
        *(float4*)&rr[12] = *(const float4*)&rb[12];

        float ax = c1.x, ay = c1.y;
        #pragma unroll
        for (int p = 0; p < 16; ++p) {
            ax = fmaf(rr[p], w0[p], ax);
            ay = fmaf(rr[p], w1[p], ay);
        }
        if (tbk != 0.0f) {                 // wave-uniform branch, ~1% taken
            ax = fmaf(tbk, w0[16], ax);
            ay = fmaf(tbk, w1[16], ay);
        }
        union { float2 f; unsigned long long u; } cv;
        cv.f = make_float2(fmaf(ax, rstd, bb0), fmaf(ay, rstd, bb1));
        __builtin_nontemporal_store(cv.u, outp + (size_t)k * 64);
    }
}

extern "C" void kernel_launch(void* const* d_in, const int* in_sizes, int n_in,
                              void* d_out, int out_size, void* d_ws, size_t ws_size,
                              hipStream_t stream) {
    const float* coords      = (const float*)d_in[0];
    const float* mask        = (const float*)d_in[1];
    const float* token_bonds = (const float*)d_in[2];
    const float* pe_w        = (const float*)d_in[3];
    const float* pe_b        = (const float*)d_in[4];
    const float* edge_w      = (const float*)d_in[5];
    const float* ln_g        = (const float*)d_in[6];
    const float* ln_b        = (const float*)d_in[7];
    const int*   t2ca        = (const int*)d_in[8];
    const int*   res_idx     = (const int*)d_in[9];
    // d_in[10] (asym_id) unused: chain_labels = zeros in the reference
    const int*   is_lig      = (const int*)d_in[11];

    float* out    = (float*)d_out;
    float* Eout   = out;                               // NEDGE * 128
    float* eidx_f = out + (size_t)NEDGE * EDGE_C_;     // NEDGE (ints as floats)
    float* dneb   = eidx_f + NEDGE;                    // NEDGE

    // workspace layout (floats); float4-read tables kept 16B-aligned
    float4* X4  = (float4*)d_ws;                       // NROWS float4
    float* Wg   = (float*)d_ws + (size_t)NROWS * 4;    // 17*128
    float* C1g  = Wg + 17 * 128;                       // 65*128
    float* T12  = C1g + 65 * 128;                      // 1040
    float* A22  = T12 + 1040;                          // 256
    float* A23  = A22 + 256;                           // 16
    float* V0   = A23 + 16;                            // 65
    float* Tb1  = V0 + 65;                             // 65
    float* A33  = Tb1 + 65;                            // 1

    hipLaunchKernelGGL(x_kernel, dim3(NROWS / 256), dim3(256), 0, stream,
                       coords, mask, t2ca, X4);
    hipLaunchKernelGGL(prep_kernel, dim3(1), dim3(256), 0, stream,
                       pe_w, pe_b, edge_w, ln_g, Wg, C1g, T12, A22, A23, V0, Tb1, A33);
    hipLaunchKernelGGL(knn_kernel, dim3(NROWS / 4), dim3(256), 0, stream,
                       X4, eidx_f, dneb);
    hipLaunchKernelGGL(edge_kernel, dim3(NROWS / 4), dim3(256), 0, stream,
                       eidx_f, dneb, token_bonds, C1g, Wg, V0, T12, Tb1,
                       A22, A23, A33, ln_b, res_idx, is_lig, Eout);
}